// Round 1
// baseline (78.243 us; speedup 1.0000x reference)
//
#include <hip/hip_runtime.h>
#include <math.h>

// Problem constants (match reference)
#define Hh 121
#define Ww 121
#define NPI 200          // N_INTERP
#define Bb 8
#define Ee 225
#define NPIX (Hh * Ww)   // 14641
#define PBLK 58          // ceil(14641 / 256) pixel-blocks per batch

#define RPD      280.0f                  // RET_PER_DVA
#define XLOWc   (-15.0f * 280.0f)        // -4200
#define STEPc   (8400.0f / 199.0f)       // STEP_X == STEP_Y
#define ODXc    (15.5f * 280.0f)         // OD_OFF_X = 4340
#define PIc      3.14159265358979323846f
#define TEMP1c  (4.0f * PIc)
#define NHL     (-0.72134752044448170368f)  // -0.5 * log2(e)

#if __has_builtin(__builtin_amdgcn_exp2f)
#define EXP2F(x) __builtin_amdgcn_exp2f(x)
#else
#define EXP2F(x) exp2f(x)
#endif

// One fused kernel:
//   phase 1: threads 0..224 compute per-(batch, electrode) quantities into LDS
//            (redundant per block — cheap: a few sin/cos/pow per thread)
//   phase 2: each thread renders one output pixel, looping over 225 electrodes
//            with broadcast LDS reads (same address across the wave -> free).
// Per-electrode LDS record (8 floats, 32 B, float4-aligned):
//   [0] center_x  [1] center_y
//   [2] -0.5*log2e*inv00   [3] -log2e*inv01   [4] -0.5*log2e*inv11
//   [5] bright    [6,7] pad
extern "C" __global__ void __launch_bounds__(256)
mvg_fused(const float* __restrict__ stim, const float* __restrict__ params,
          const float* __restrict__ elec_x, const float* __restrict__ elec_y,
          const float* __restrict__ slopes, float* __restrict__ out)
{
    __shared__ __align__(16) float sd[Ee * 8];

    const int b   = blockIdx.y;
    const int tid = threadIdx.x;

    if (tid < Ee) {
        const float* p = params + b * 13;
        const float rho = p[0], lam = p[1], osc = p[2];
        const float a0 = p[3], a1 = p[4], a2 = p[5], a3 = p[6], a4 = p[7];
        const float impx = p[8], impy = p[9], rot = p[10], locx = p[11];

        const float cr = cosf(rot), sr = sinf(rot);
        const float exl = elec_x[tid], eyl = elec_y[tid];
        const float exv = exl * cr - eyl * sr + impx;
        const float eyv = exl * sr + eyl * cr + impy;

        // bilinear interp of slopes at (qx, qy)
        const float offx = locx - ODXc;
        const float qx = (exv - offx - XLOWc) / STEPc;
        const float qy = (eyv - XLOWc) / STEPc;            // YLOW == XLOW
        const float fx = fminf(fmaxf(floorf(qx), 0.0f), (float)(NPI - 2));
        const float fy = fminf(fmaxf(floorf(qy), 0.0f), (float)(NPI - 2));
        const int ix = (int)fx, iy = (int)fy;
        const float ax = fminf(fmaxf(qx - fx, 0.0f), 1.0f);
        const float ay = fminf(fmaxf(qy - fy, 0.0f), 1.0f);
        const float g00 = slopes[iy * NPI + ix];
        const float g01 = slopes[iy * NPI + ix + 1];
        const float g10 = slopes[(iy + 1) * NPI + ix];
        const float g11 = slopes[(iy + 1) * NPI + ix + 1];
        const float top = g00 + ax * (g01 - g00);
        const float bot = g10 + ax * (g11 - g10);
        float th = top + ay * (bot - top);
        th = (th < -0.5f * PIc) ? th + PIc : th;
        th *= osc;

        const float* st = stim + (b * Ee + tid) * 3;
        const float freq = st[0], amp = st[1], pdur = st[2];

        const float rho_s = fmaxf(rho * amp * a3, 1.0f);
        float lam_s = lam * powf(0.45f, -a4) * powf(pdur, a4);
        lam_s = fminf(fmaxf(lam_s, 0.0f), 0.99f);
        const float bright =
            (amp > 0.25f) ? (a0 * powf(fmaxf(amp, 1e-5f), a1) + a2 * freq) : 0.0f;

        const float temp2 = sqrtf(1.0f - lam_s * lam_s);
        const float sy_ = rho_s / (TEMP1c * temp2);
        const float sx_ = rho_s * temp2 / TEMP1c;
        const float s = sinf(th), c = cosf(th);
        const float cov00 = sx_ * c * c + sy_ * s * s;
        const float cov01 = (sx_ - sy_) * s * c;
        const float cov11 = sx_ * s * s + sy_ * c * c;
        const float det = cov00 * cov11 - cov01 * cov01;
        const float i00 = cov11 / det;
        const float i01 = -cov01 / det;
        const float i11 = cov00 / det;

        const float cx = (exv / RPD + 15.0f) * 4.0f;             // (x/RPD - XRANGE0)/XYSTEP
        const float cy = (float)Hh - (eyv / RPD + 15.0f) * 4.0f;

        float* o = sd + tid * 8;
        o[0] = cx;
        o[1] = cy;
        o[2] = i00 * NHL;          // coeff for dx*dx
        o[3] = i01 * 2.0f * NHL;   // coeff for dx*dy
        o[4] = i11 * NHL;          // coeff for dy*dy
        o[5] = bright;
        o[6] = 0.0f;
        o[7] = 0.0f;
    }
    __syncthreads();

    const int pix = blockIdx.x * 256 + tid;
    if (pix < NPIX) {
        const int i = pix / Ww;
        const int j = pix - i * Ww;
        // out[b,i,j] sums over e of bright*exp2(dx^2*A + dx*dy*B + dy^2*C)
        // with dx = j - cx, dy = (120 - i) - cy  (derived from pixelgrid/flip)
        const float px = (float)j;
        const float py = (float)(Ww - 1 - i);

        float acc0 = 0.0f, acc1 = 0.0f, acc2 = 0.0f;
        #pragma unroll 1
        for (int e = 0; e < Ee; e += 3) {
            {
                const float4 v = *(const float4*)(sd + (e + 0) * 8);
                const float2 w = *(const float2*)(sd + (e + 0) * 8 + 4);
                const float dx = px - v.x, dy = py - v.y;
                const float t = dx * dx * v.z + dx * dy * v.w + dy * dy * w.x;
                acc0 += w.y * EXP2F(t);
            }
            {
                const float4 v = *(const float4*)(sd + (e + 1) * 8);
                const float2 w = *(const float2*)(sd + (e + 1) * 8 + 4);
                const float dx = px - v.x, dy = py - v.y;
                const float t = dx * dx * v.z + dx * dy * v.w + dy * dy * w.x;
                acc1 += w.y * EXP2F(t);
            }
            {
                const float4 v = *(const float4*)(sd + (e + 2) * 8);
                const float2 w = *(const float2*)(sd + (e + 2) * 8 + 4);
                const float dx = px - v.x, dy = py - v.y;
                const float t = dx * dx * v.z + dx * dy * v.w + dy * dy * w.x;
                acc2 += w.y * EXP2F(t);
            }
        }
        out[b * NPIX + pix] = acc0 + acc1 + acc2;
    }
}

extern "C" void kernel_launch(void* const* d_in, const int* in_sizes, int n_in,
                              void* d_out, int out_size, void* d_ws, size_t ws_size,
                              hipStream_t stream) {
    const float* stim   = (const float*)d_in[0];  // (8, 225, 3)
    const float* params = (const float*)d_in[1];  // (8, 13)
    const float* ex     = (const float*)d_in[2];  // (1, 225)
    const float* ey     = (const float*)d_in[3];  // (1, 225)
    const float* slopes = (const float*)d_in[4];  // (200, 200)
    // d_in[5] = pixelgrid: unused, indices derived analytically
    float* out = (float*)d_out;                   // (8, 121, 121) fp32

    dim3 grid(PBLK, Bb);  // 58 pixel-chunks x 8 batches
    mvg_fused<<<grid, 256, 0, stream>>>(stim, params, ex, ey, slopes, out);
}